// Round 5
// baseline (113.318 us; speedup 1.0000x reference)
//
#include <hip/hip_runtime.h>

// fastmax linear attention (causal, p=1): chunked scan + bf16 MFMA matmuls.
// b=2, h=8, n=8192, d=32 -> bh=16, chunks of C=64 rows, 128 chunks per bh.
// State per chunk: KV (32x32, [d1][d2]) + Ksum (32) + Vsum (32) = 1088 f32.
// Numerator matmuls (S=QK^T, T.V, Q.KV, KV=K^T.V) in bf16 MFMA; the
// denominator (tiny values possible!) is computed entirely in fp32.
// Scan over chunks: one thread per (bh, element) stream, exclusive in-place.

#define D      32
#define C      64
#define NCHUNK 128
#define BH     16
#define NSEQ   8192
#define STATE  1088

typedef __attribute__((ext_vector_type(8))) short bf16x8;
typedef __attribute__((ext_vector_type(4))) float f32x4;

__device__ __forceinline__ unsigned short f2bf(float x) {
  union { float f; unsigned u; } c; c.f = x;
  unsigned r = (c.u + 0x7FFFu + ((c.u >> 16) & 1u)) >> 16;   // RNE
  return (unsigned short)r;
}

// ---------------------------------------------------------------------------
// Kernel 1: per-chunk state sums via MFMA.  grid = BH*NCHUNK, 256 threads.
// KV = K^T.V (32x32, K=64) as 4 16x16 tiles; ksum/vsum fp32 in registers.
// ---------------------------------------------------------------------------
__global__ __launch_bounds__(256) void chunk_state_kernel(
    const float* __restrict__ k, const float* __restrict__ v,
    float* __restrict__ states) {
  int blk = blockIdx.x;
  int bh  = blk >> 7;
  int c   = blk & 127;
  size_t off = ((size_t)bh * NSEQ + (size_t)c * C) * D;
  const float* kp = k + off;
  const float* vp = v + off;

  __shared__ __align__(16) unsigned short kT[D * 72];  // kT[e][j], stride 72
  __shared__ __align__(16) unsigned short vT[D * 72];  // vT[e][j]
  __shared__ __align__(16) float psK[256];
  __shared__ __align__(16) float psV[256];

  int t = threadIdx.x;
  int e = t & 31;               // fixed column per thread
  float sk = 0.f, sv = 0.f;
  for (int r = 0; r < 8; ++r) {
    int idx = t + r * 256;      // coalesced; j = (t>>5) + 8r, same e
    int j = idx >> 5;
    float kvv = kp[idx], vvv = vp[idx];
    kT[e * 72 + j] = f2bf(kvv);
    vT[e * 72 + j] = f2bf(vvv);
    sk += kvv; sv += vvv;
  }
  psK[t] = sk; psV[t] = sv;
  __syncthreads();

  int lane = t & 63, w = t >> 6;
  int m16 = lane & 15, quad = lane >> 4;
  int mb = w >> 1, nb = w & 1;            // tile (d1-block, d2-block)
  f32x4 acc = {0.f, 0.f, 0.f, 0.f};
#pragma unroll
  for (int kb = 0; kb < 2; ++kb) {        // K=64 in two k-steps
    bf16x8 a = *(const bf16x8*)&kT[(16 * mb + m16) * 72 + kb * 32 + quad * 8];
    bf16x8 b = *(const bf16x8*)&vT[(16 * nb + m16) * 72 + kb * 32 + quad * 8];
    acc = __builtin_amdgcn_mfma_f32_16x16x32_bf16(a, b, acc, 0, 0, 0);
  }
  float* st = states + (size_t)blk * STATE;
#pragma unroll
  for (int reg = 0; reg < 4; ++reg) {     // row=d1, col=d2 -> st[d1*32+d2]
    int d1 = 16 * mb + quad * 4 + reg;
    int d2 = 16 * nb + m16;
    st[d1 * 32 + d2] = acc[reg];
  }
  if (t < 64) {                           // fp32-exact k/v column sums
    int ee = t & 31;
    float s = 0.f;
    if (t < 32) {
#pragma unroll
      for (int g = 0; g < 8; ++g) s += psK[ee + 32 * g];
      st[1024 + ee] = s;
    } else {
#pragma unroll
      for (int g = 0; g < 8; ++g) s += psV[ee + 32 * g];
      st[1056 + ee] = s;
    }
  }
}

// ---------------------------------------------------------------------------
// Kernel 2: in-place exclusive scan over chunks, one thread per (bh, e)
// stream.  grid = BH*STATE/256 = 68 blocks.  Batches of 16 keep 16 loads in
// flight; the serial chain is register adds only.
// ---------------------------------------------------------------------------
__global__ __launch_bounds__(256) void scan_kernel(float* __restrict__ states) {
  int gidx = blockIdx.x * 256 + threadIdx.x;   // 0 .. BH*STATE-1 (exact fit)
  int bh = gidx / STATE;
  int e  = gidx % STATE;
  float* base = states + (size_t)bh * NCHUNK * STATE + e;
  float a = 0.f;
#pragma unroll 1
  for (int c0 = 0; c0 < NCHUNK; c0 += 16) {
    float s[16];
#pragma unroll
    for (int r = 0; r < 16; ++r) s[r] = base[(size_t)(c0 + r) * STATE];
#pragma unroll
    for (int r = 0; r < 16; ++r) { float tv = s[r]; s[r] = a; a += tv; }
#pragma unroll
    for (int r = 0; r < 16; ++r) base[(size_t)(c0 + r) * STATE] = s[r];
  }
}

// ---------------------------------------------------------------------------
// Kernel 3: MFMA output kernel.  grid = BH*NCHUNK, 256 threads (4 waves).
// Wave w owns output rows 16w..16w+15.
//   S = Q.K^T (bf16 MFMA, causal mask) -> T=1+S -> Tbf (bf16, LDS)
//   O = Q.KVpre (MFMA) + T.V (MFMA);  epilogue adds vpre, scales by 1/den.
//   den (fp32 only): cN+i+1 + q_i.(kpre + cumsum_local(k)_i) via fp32
//   column-scan of k + per-row fp32 dots.
// ---------------------------------------------------------------------------
__global__ __launch_bounds__(256) void output_kernel(
    const float* __restrict__ q, const float* __restrict__ k,
    const float* __restrict__ v, const float* __restrict__ states,
    float* __restrict__ out) {
  int blk = blockIdx.x;
  int bh  = blk >> 7;
  int c   = blk & 127;
  size_t off = ((size_t)bh * NSEQ + (size_t)c * C) * D;
  const float* qp = q + off;
  const float* kp = k + off;
  const float* vp = v + off;
  const float* st = states + (size_t)blk * STATE;

  __shared__ __align__(16) unsigned short qbf[C * 40];    // [i][dd]
  __shared__ __align__(16) unsigned short kbf[C * 40];    // [j][dd]
  __shared__ __align__(16) unsigned short vTbf[D * 72];   // [e][j]
  __shared__ __align__(16) unsigned short kvTbf[D * 40];  // [e][dd]
  __shared__ __align__(16) unsigned short Tbf[C * 72];    // [i][j]
  __shared__ __align__(16) float q_s[C * 36];             // fp32 q rows
  __shared__ __align__(16) float kc_s[C * 36];            // fp32 k -> cumsum+kpre
  __shared__ __align__(16) float gtot[8 * 32];
  __shared__ __align__(16) float kpre_s[D], vpre_s[D], invdiv_s[C];

  int t = threadIdx.x;
  int e = t & 31;

  // ---- staging ------------------------------------------------------------
  for (int z = t; z < (C * 72) / 8; z += 256)   // zero Tbf (masked region read)
    ((uint4*)Tbf)[z] = make_uint4(0, 0, 0, 0);
  for (int r = 0; r < 8; ++r) {
    int idx = t + r * 256;
    int j = idx >> 5;                  // same e per thread
    float qv = qp[idx], kv = kp[idx], vv = vp[idx];
    q_s[j * 36 + e]  = qv;  qbf[j * 40 + e] = f2bf(qv);
    kc_s[j * 36 + e] = kv;  kbf[j * 40 + e] = f2bf(kv);
    vTbf[e * 72 + j] = f2bf(vv);
  }
  for (int r = 0; r < 4; ++r) {
    int idx = t + r * 256;
    int dd = idx >> 5;                 // st is KV[d1][d2], d1-major
    kvTbf[e * 40 + dd] = f2bf(st[idx]);
  }
  if (t < 32)      kpre_s[t]      = st[1024 + t];
  else if (t < 64) vpre_s[t - 32] = st[1024 + t];
  __syncthreads();

  int lane = t & 63, w = t >> 6;
  int m16 = lane & 15, quad = lane >> 4;

  // ---- part 1: S tiles -> Tbf;  scan phase a (per-thread cumsum of 8 rows) -
  const bf16x8 aQ = *(const bf16x8*)&qbf[(16 * w + m16) * 40 + quad * 8];
  for (int jb = 0; jb <= w; ++jb) {
    bf16x8 bK = *(const bf16x8*)&kbf[(16 * jb + m16) * 40 + quad * 8];
    f32x4 cS = {0.f, 0.f, 0.f, 0.f};
    cS = __builtin_amdgcn_mfma_f32_16x16x32_bf16(aQ, bK, cS, 0, 0, 0);
    int jcol = 16 * jb + m16;
#pragma unroll
    for (int reg = 0; reg < 4; ++reg) {
      int i = 16 * w + quad * 4 + reg;
      float tv = (jcol <= i) ? (1.f + cS[reg]) : 0.f;
      Tbf[i * 72 + jcol] = f2bf(tv);
    }
  }
  int rg = t >> 5;                     // row-group 0..7 (rows rg*8..rg*8+7)
  float vals[8];
  {
    float run = 0.f;
#pragma unroll
    for (int r = 0; r < 8; ++r) {
      vals[r] = kc_s[(rg * 8 + r) * 36 + e];
      run += vals[r];
    }
    gtot[rg * 32 + e] = run;
  }
  __syncthreads();

  // ---- part 2: scan phase b (apply group offsets + kpre, write cumsum) ----
  {
    float offv = kpre_s[e];
    for (int g = 0; g < rg; ++g) offv += gtot[g * 32 + e];
    float cacc = offv;
#pragma unroll
    for (int r = 0; r < 8; ++r) {
      cacc += vals[r];
      kc_s[(rg * 8 + r) * 36 + e] = cacc;   // kpre + cumsum_local(k)
    }
  }
  __syncthreads();

  // ---- part 3: fp32 den (wave 0) + O MFMAs (all waves) --------------------
  if (t < 64) {
    int i = t;
    float dp = 0.f;
#pragma unroll
    for (int d4 = 0; d4 < 8; ++d4) {
      float4 qv = *(const float4*)&q_s[i * 36 + 4 * d4];
      float4 kc = *(const float4*)&kc_s[i * 36 + 4 * d4];
      dp += qv.x * kc.x + qv.y * kc.y + qv.z * kc.z + qv.w * kc.w;
    }
    invdiv_s[i] = 1.f / ((float)(c * C + i + 1) + dp);
  }
  f32x4 o0 = {0.f, 0.f, 0.f, 0.f}, o1 = {0.f, 0.f, 0.f, 0.f};
  {
    bf16x8 b0 = *(const bf16x8*)&kvTbf[(m16)      * 40 + quad * 8];
    bf16x8 b1 = *(const bf16x8*)&kvTbf[(16 + m16) * 40 + quad * 8];
    o0 = __builtin_amdgcn_mfma_f32_16x16x32_bf16(aQ, b0, o0, 0, 0, 0);
    o1 = __builtin_amdgcn_mfma_f32_16x16x32_bf16(aQ, b1, o1, 0, 0, 0);
  }
  int kbcnt = (w >= 2) ? 2 : 1;        // T is zero past column 16w+15
  for (int kb = 0; kb < kbcnt; ++kb) {
    bf16x8 aT = *(const bf16x8*)&Tbf[(16 * w + m16) * 72 + kb * 32 + quad * 8];
    bf16x8 b0 = *(const bf16x8*)&vTbf[(m16)      * 72 + kb * 32 + quad * 8];
    bf16x8 b1 = *(const bf16x8*)&vTbf[(16 + m16) * 72 + kb * 32 + quad * 8];
    o0 = __builtin_amdgcn_mfma_f32_16x16x32_bf16(aT, b0, o0, 0, 0, 0);
    o1 = __builtin_amdgcn_mfma_f32_16x16x32_bf16(aT, b1, o1, 0, 0, 0);
  }
  __syncthreads();

  // ---- epilogue -----------------------------------------------------------
#pragma unroll
  for (int reg = 0; reg < 4; ++reg) {
    int i = 16 * w + quad * 4 + reg;
    float id = invdiv_s[i];
    int e0 = m16, e1 = 16 + m16;
    out[off + (size_t)i * D + e0] = (vpre_s[e0] + o0[reg]) * id;
    out[off + (size_t)i * D + e1] = (vpre_s[e1] + o1[reg]) * id;
  }
}

// ---------------------------------------------------------------------------
extern "C" void kernel_launch(void* const* d_in, const int* in_sizes, int n_in,
                              void* d_out, int out_size, void* d_ws, size_t ws_size,
                              hipStream_t stream) {
  const float* q = (const float*)d_in[0];
  const float* k = (const float*)d_in[1];
  const float* v = (const float*)d_in[2];
  float* out    = (float*)d_out;
  float* states = (float*)d_ws;                                  // 8.9 MB

  chunk_state_kernel<<<BH * NCHUNK, 256, 0, stream>>>(k, v, states);
  scan_kernel<<<(BH * STATE) / 256, 256, 0, stream>>>(states);
  output_kernel<<<BH * NCHUNK, 256, 0, stream>>>(q, k, v, states, out);
}

// Round 7
// 108.862 us; speedup vs baseline: 1.0409x; 1.0409x over previous
//
#include <hip/hip_runtime.h>

// fastmax linear attention (causal, p=1): chunked scan + bf16 MFMA matmuls.
// b=2, h=8, n=8192, d=32 -> bh=16, chunks of C=64 rows, 128 chunks per bh.
// State per chunk: KV (32x32, [d1][d2]) + Ksum (32) + Vsum (32) = 1088 f32.
// Numerator matmuls in bf16 MFMA; denominator entirely fp32.
// float4 global staging, packed LDS writes, column-permuted V/KV for float2
// output stores, 32-wide scan batches.  (R6 fix: kpre/vpre tail staged by
// threads 0..15 — the R5 version used t>=256 branches that never ran.)

#define D      32
#define C      64
#define NCHUNK 128
#define BH     16
#define NSEQ   8192
#define STATE  1088

typedef __attribute__((ext_vector_type(8))) short bf16x8;
typedef __attribute__((ext_vector_type(4))) float f32x4;
typedef __attribute__((ext_vector_type(4))) unsigned short u16x4;

__device__ __forceinline__ unsigned short f2bf(float x) {
  union { float f; unsigned u; } c; c.f = x;
  unsigned r = (c.u + 0x7FFFu + ((c.u >> 16) & 1u)) >> 16;   // RNE
  return (unsigned short)r;
}

// column permutation: MFMA output col n = original col (n<16 ? 2n : 2(n-16)+1)
// staging: element with original col e goes to row n(e) = (e&1) ? 16+(e>>1) : (e>>1)
__device__ __forceinline__ int permcol(int e) {
  return (e & 1) ? (16 + (e >> 1)) : (e >> 1);
}

// ---------------------------------------------------------------------------
// Kernel 1: per-chunk state sums via MFMA.  grid = BH*NCHUNK, 256 threads.
// ---------------------------------------------------------------------------
__global__ __launch_bounds__(256) void chunk_state_kernel(
    const float* __restrict__ k, const float* __restrict__ v,
    float* __restrict__ states) {
  int blk = blockIdx.x;
  const float4* kp = (const float4*)k + (size_t)blk * 512;
  const float4* vp = (const float4*)v + (size_t)blk * 512;

  __shared__ __align__(16) unsigned short kT[D * 72];  // kT[e][j]
  __shared__ __align__(16) unsigned short vT[D * 72];  // vT[e][j]
  __shared__ __align__(16) float4 psK[256];            // per-thread col partials
  __shared__ __align__(16) float4 psV[256];

  int t  = threadIdx.x;
  int j0 = t >> 3;            // row of first float4
  int cb = (t & 7) * 4;       // column base
  float4 kA = kp[t], kB = kp[t + 256];
  float4 vA = vp[t], vB = vp[t + 256];

  const float* ka = &kA.x; const float* kb = &kB.x;
  const float* va = &vA.x; const float* vb = &vB.x;
#pragma unroll
  for (int cc = 0; cc < 4; ++cc) {
    kT[(cb + cc) * 72 + j0]      = f2bf(ka[cc]);
    kT[(cb + cc) * 72 + j0 + 32] = f2bf(kb[cc]);
    vT[(cb + cc) * 72 + j0]      = f2bf(va[cc]);
    vT[(cb + cc) * 72 + j0 + 32] = f2bf(vb[cc]);
  }
  psK[t] = make_float4(kA.x + kB.x, kA.y + kB.y, kA.z + kB.z, kA.w + kB.w);
  psV[t] = make_float4(vA.x + vB.x, vA.y + vB.y, vA.z + vB.z, vA.w + vB.w);
  __syncthreads();

  int lane = t & 63, w = t >> 6;
  int m16 = lane & 15, quad = lane >> 4;
  int mb = w >> 1, nb = w & 1;
  f32x4 acc = {0.f, 0.f, 0.f, 0.f};
#pragma unroll
  for (int kb2 = 0; kb2 < 2; ++kb2) {
    bf16x8 a = *(const bf16x8*)&kT[(16 * mb + m16) * 72 + kb2 * 32 + quad * 8];
    bf16x8 b = *(const bf16x8*)&vT[(16 * nb + m16) * 72 + kb2 * 32 + quad * 8];
    acc = __builtin_amdgcn_mfma_f32_16x16x32_bf16(a, b, acc, 0, 0, 0);
  }
  float* st = states + (size_t)blk * STATE;
#pragma unroll
  for (int reg = 0; reg < 4; ++reg) {
    int d1 = 16 * mb + quad * 4 + reg;
    int d2 = 16 * nb + m16;
    st[d1 * 32 + d2] = acc[reg];
  }
  if (t < 64) {                           // fp32-exact k/v column sums
    int ee = t & 31;
    const float* ps = (t < 32) ? (const float*)psK : (const float*)psV;
    float s = 0.f;
#pragma unroll
    for (int m = 0; m < 32; ++m) s += ps[ee + 32 * m];
    st[1024 + ((t < 32) ? ee : 32 + ee)] = s;
  }
}

// ---------------------------------------------------------------------------
// Kernel 2: in-place exclusive scan over chunks, one thread per (bh, e)
// stream.  grid = BH*STATE/256 = 68 blocks.
// ---------------------------------------------------------------------------
__global__ __launch_bounds__(256) void scan_kernel(float* __restrict__ states) {
  int gidx = blockIdx.x * 256 + threadIdx.x;
  int bh = gidx / STATE;
  int e  = gidx % STATE;
  float* base = states + (size_t)bh * NCHUNK * STATE + e;
  float a = 0.f;
#pragma unroll 1
  for (int c0 = 0; c0 < NCHUNK; c0 += 32) {
    float s[32];
#pragma unroll
    for (int r = 0; r < 32; ++r) s[r] = base[(size_t)(c0 + r) * STATE];
#pragma unroll
    for (int r = 0; r < 32; ++r) { float tv = s[r]; s[r] = a; a += tv; }
#pragma unroll
    for (int r = 0; r < 32; ++r) base[(size_t)(c0 + r) * STATE] = s[r];
  }
}

// ---------------------------------------------------------------------------
// Kernel 3: MFMA output kernel.  grid = BH*NCHUNK, 256 threads (4 waves).
// ---------------------------------------------------------------------------
__global__ __launch_bounds__(256) void output_kernel(
    const float* __restrict__ q, const float* __restrict__ k,
    const float* __restrict__ v, const float* __restrict__ states,
    float* __restrict__ out) {
  int blk = blockIdx.x;
  int c   = blk & 127;
  size_t off = (size_t)blk * (C * D);
  const float4* qp4 = (const float4*)q + (size_t)blk * 512;
  const float4* kp4 = (const float4*)k + (size_t)blk * 512;
  const float4* vp4 = (const float4*)v + (size_t)blk * 512;
  const float4* st4 = (const float4*)(states + (size_t)blk * STATE);

  __shared__ __align__(16) unsigned short qbf[C * 40];    // [i][dd]
  __shared__ __align__(16) unsigned short kbf[C * 40];    // [j][dd]
  __shared__ __align__(16) unsigned short vTbf[D * 72];   // [n][j], permuted cols
  __shared__ __align__(16) unsigned short kvTbf[D * 40];  // [n][dd], permuted cols
  __shared__ __align__(16) unsigned short Tbf[C * 72];    // [i][j]
  __shared__ __align__(16) float q_s[C * 36];             // fp32 q rows
  __shared__ __align__(16) float kc_s[C * 36];            // fp32 k -> cumsum+kpre
  __shared__ __align__(16) float gtot[8 * 32];
  __shared__ __align__(16) float kpre_s[D], vpre_s[D], invdiv_s[C];

  int t  = threadIdx.x;
  int j0 = t >> 3;
  int cb = (t & 7) * 4;

  // ---- issue all global loads first ---------------------------------------
  float4 qA = qp4[t], qB = qp4[t + 256];
  float4 kA = kp4[t], kB = kp4[t + 256];
  float4 vA = vp4[t], vB = vp4[t + 256];
  float4 sv = st4[t];                          // KV[d1][d2] block
  float4 tail = make_float4(0.f, 0.f, 0.f, 0.f);
  if (t < 16) tail = st4[256 + t];             // kpre (8) + vpre (8)

  // zero Tbf while loads are in flight (masked region must read 0)
  for (int z = t; z < (C * 72) / 8; z += 256)
    ((uint4*)Tbf)[z] = make_uint4(0, 0, 0, 0);

  // ---- convert + stage ----------------------------------------------------
  *(float4*)&q_s[j0 * 36 + cb]        = qA;
  *(float4*)&q_s[(j0 + 32) * 36 + cb] = qB;
  *(float4*)&kc_s[j0 * 36 + cb]        = kA;
  *(float4*)&kc_s[(j0 + 32) * 36 + cb] = kB;
  *(u16x4*)&qbf[j0 * 40 + cb] =
      (u16x4){f2bf(qA.x), f2bf(qA.y), f2bf(qA.z), f2bf(qA.w)};
  *(u16x4*)&qbf[(j0 + 32) * 40 + cb] =
      (u16x4){f2bf(qB.x), f2bf(qB.y), f2bf(qB.z), f2bf(qB.w)};
  *(u16x4*)&kbf[j0 * 40 + cb] =
      (u16x4){f2bf(kA.x), f2bf(kA.y), f2bf(kA.z), f2bf(kA.w)};
  *(u16x4*)&kbf[(j0 + 32) * 40 + cb] =
      (u16x4){f2bf(kB.x), f2bf(kB.y), f2bf(kB.z), f2bf(kB.w)};
  {
    const float* va = &vA.x; const float* vb = &vB.x;
    const float* sp = &sv.x;
#pragma unroll
    for (int cc = 0; cc < 4; ++cc) {
      int n = permcol(cb + cc);
      vTbf[n * 72 + j0]      = f2bf(va[cc]);
      vTbf[n * 72 + j0 + 32] = f2bf(vb[cc]);
      kvTbf[n * 40 + j0]     = f2bf(sp[cc]);   // KV[d1=j0][d2=cb+cc]
    }
  }
  if (t < 8)            ((float4*)kpre_s)[t]     = tail;
  else if (t < 16)      ((float4*)vpre_s)[t - 8] = tail;
  __syncthreads();

  int lane = t & 63, w = t >> 6;
  int m16 = lane & 15, quad = lane >> 4;

  // ---- part 1: S tiles -> Tbf;  scan phase a ------------------------------
  const bf16x8 aQ = *(const bf16x8*)&qbf[(16 * w + m16) * 40 + quad * 8];
  for (int jb = 0; jb <= w; ++jb) {
    bf16x8 bK = *(const bf16x8*)&kbf[(16 * jb + m16) * 40 + quad * 8];
    f32x4 cS = {0.f, 0.f, 0.f, 0.f};
    cS = __builtin_amdgcn_mfma_f32_16x16x32_bf16(aQ, bK, cS, 0, 0, 0);
    int jcol = 16 * jb + m16;
#pragma unroll
    for (int reg = 0; reg < 4; ++reg) {
      int i = 16 * w + quad * 4 + reg;
      float tv = (jcol <= i) ? (1.f + cS[reg]) : 0.f;
      Tbf[i * 72 + jcol] = f2bf(tv);
    }
  }
  int rg = t >> 5;                     // row-group 0..7
  int e  = t & 31;
  float vals[8];
  {
    float run = 0.f;
#pragma unroll
    for (int r = 0; r < 8; ++r) {
      vals[r] = kc_s[(rg * 8 + r) * 36 + e];
      run += vals[r];
    }
    gtot[rg * 32 + e] = run;
  }
  __syncthreads();

  // ---- part 2: apply group offsets + kpre, write k-cumsum -----------------
  {
    float offv = kpre_s[e];
    for (int g = 0; g < rg; ++g) offv += gtot[g * 32 + e];
    float cacc = offv;
#pragma unroll
    for (int r = 0; r < 8; ++r) {
      cacc += vals[r];
      kc_s[(rg * 8 + r) * 36 + e] = cacc;   // kpre + cumsum_local(k)
    }
  }
  __syncthreads();

  // ---- part 3: fp32 den (wave 0) + O MFMAs (all waves) --------------------
  if (t < 64) {
    int i = t;
    float dp = 0.f;
#pragma unroll
    for (int d4 = 0; d4 < 8; ++d4) {
      float4 qv = *(const float4*)&q_s[i * 36 + 4 * d4];
      float4 kc = *(const float4*)&kc_s[i * 36 + 4 * d4];
      dp += qv.x * kc.x + qv.y * kc.y + qv.z * kc.z + qv.w * kc.w;
    }
    invdiv_s[i] = 1.f / ((float)(c * C + i + 1) + dp);
  }
  f32x4 o0 = {0.f, 0.f, 0.f, 0.f}, o1 = {0.f, 0.f, 0.f, 0.f};
  {
    bf16x8 b0 = *(const bf16x8*)&kvTbf[(m16)      * 40 + quad * 8];
    bf16x8 b1 = *(const bf16x8*)&kvTbf[(16 + m16) * 40 + quad * 8];
    o0 = __builtin_amdgcn_mfma_f32_16x16x32_bf16(aQ, b0, o0, 0, 0, 0);
    o1 = __builtin_amdgcn_mfma_f32_16x16x32_bf16(aQ, b1, o1, 0, 0, 0);
  }
  int kbcnt = (w >= 2) ? 2 : 1;        // T is zero past column 16w+15
  for (int kb = 0; kb < kbcnt; ++kb) {
    bf16x8 aT = *(const bf16x8*)&Tbf[(16 * w + m16) * 72 + kb * 32 + quad * 8];
    bf16x8 b0 = *(const bf16x8*)&vTbf[(m16)      * 72 + kb * 32 + quad * 8];
    bf16x8 b1 = *(const bf16x8*)&vTbf[(16 + m16) * 72 + kb * 32 + quad * 8];
    o0 = __builtin_amdgcn_mfma_f32_16x16x32_bf16(aT, b0, o0, 0, 0, 0);
    o1 = __builtin_amdgcn_mfma_f32_16x16x32_bf16(aT, b1, o1, 0, 0, 0);
  }
  __syncthreads();

  // ---- epilogue: columns 2*m16, 2*m16+1 -> float2 stores ------------------
  int e0 = 2 * m16;
#pragma unroll
  for (int reg = 0; reg < 4; ++reg) {
    int i = 16 * w + quad * 4 + reg;
    float id = invdiv_s[i];
    float2 o;
    o.x = (vpre_s[e0]     + o0[reg]) * id;
    o.y = (vpre_s[e0 + 1] + o1[reg]) * id;
    *(float2*)&out[off + (size_t)i * D + e0] = o;
  }
}

// ---------------------------------------------------------------------------
extern "C" void kernel_launch(void* const* d_in, const int* in_sizes, int n_in,
                              void* d_out, int out_size, void* d_ws, size_t ws_size,
                              hipStream_t stream) {
  const float* q = (const float*)d_in[0];
  const float* k = (const float*)d_in[1];
  const float* v = (const float*)d_in[2];
  float* out    = (float*)d_out;
  float* states = (float*)d_ws;                                  // 8.9 MB

  chunk_state_kernel<<<BH * NCHUNK, 256, 0, stream>>>(k, v, states);
  scan_kernel<<<(BH * STATE) / 256, 256, 0, stream>>>(states);
  output_kernel<<<BH * NCHUNK, 256, 0, stream>>>(q, k, v, states, out);
}